// Round 14
// baseline (182.147 us; speedup 1.0000x reference)
//
#include <hip/hip_runtime.h>

// Problem sizes (fixed by the reference)
#define BDIM 8
#define QDIM 1024
#define KDIM 1024
#define HDIM 64   // = DQ = DK = DV
#define KTPC 2    // k-tiles (64 keys) per chunk -> uniform block cost
#define MAXCH 8   // ceil(16/KTPC)

constexpr float kLog2e = 1.4426950408889634f;
constexpr float kC2 = 2.0f * kLog2e;

// ---------------------------------------------------------------------------
// K1: both projections; emits Eq/Ek = min(exp2(kC2 * (X@W)), 2^15).
// ---------------------------------------------------------------------------
__global__ __launch_bounds__(256) void proj_both(
    const float* __restrict__ queries, const float* __restrict__ keys,
    const float* __restrict__ Wq, const float* __restrict__ Wk,
    float* __restrict__ eq, float* __restrict__ ek) {
  const int bid = blockIdx.x;
  const bool isK = bid >= 256;
  const float* X = isK ? keys : queries;
  const float* W = isK ? Wk : Wq;
  float* Y = isK ? ek : eq;
  const long long base = (long long)(bid & 255) * 32 * 64;

  __shared__ __align__(16) float xs[32][68];
  __shared__ __align__(16) float ws[64][64];
  const int t = threadIdx.x;
  {
    const int r = t >> 4, sl = t & 15;
#pragma unroll
    for (int i = 0; i < 2; ++i)
      *(float4*)&xs[r + i * 16][sl * 4] =
          *(const float4*)&X[base + (long long)(r + i * 16) * 64 + sl * 4];
#pragma unroll
    for (int i = 0; i < 4; ++i)
      *(float4*)&ws[r + i * 16][sl * 4] =
          *(const float4*)&W[(r + i * 16) * 64 + sl * 4];
  }
  __syncthreads();

  const int r = t >> 3;            // 0..31
  const int c0 = (t & 7) * 8;      // 8 output cols per thread
  float acc[8];
#pragma unroll
  for (int j = 0; j < 8; ++j) acc[j] = 0.0f;

#pragma unroll 8
  for (int d = 0; d < 64; ++d) {
    const float xv = xs[r][d];
#pragma unroll
    for (int j4 = 0; j4 < 2; ++j4) {
      float4 w4 = *(float4*)&ws[d][c0 + j4 * 4];
      acc[j4 * 4 + 0] = fmaf(xv, w4.x, acc[j4 * 4 + 0]);
      acc[j4 * 4 + 1] = fmaf(xv, w4.y, acc[j4 * 4 + 1]);
      acc[j4 * 4 + 2] = fmaf(xv, w4.z, acc[j4 * 4 + 2]);
      acc[j4 * 4 + 3] = fmaf(xv, w4.w, acc[j4 * 4 + 3]);
    }
  }
#pragma unroll
  for (int j4 = 0; j4 < 2; ++j4) {
    float4 o = make_float4(
        fminf(__builtin_amdgcn_exp2f(acc[j4 * 4 + 0] * kC2), 32768.0f),
        fminf(__builtin_amdgcn_exp2f(acc[j4 * 4 + 1] * kC2), 32768.0f),
        fminf(__builtin_amdgcn_exp2f(acc[j4 * 4 + 2] * kC2), 32768.0f),
        fminf(__builtin_amdgcn_exp2f(acc[j4 * 4 + 3] * kC2), 32768.0f));
    *(float4*)&Y[base + (long long)r * 64 + c0 + j4 * 4] = o;
  }
}

// ---------------------------------------------------------------------------
// K2: fused scores + softmax-numerator + PV over one chunk (<=2 k-tiles).
// NO K/V LDS STAGING: K/V fragments read directly from global/L2 (b-major
// worklist keeps the window L2-resident; intra-wave duplicate addresses
// coalesce; per-block working set 32 KB ~ L1). No k-loop __syncthreads.
// LDS = qs (4.25 KB) + rotated ps (4 KB). Thread (tq=t>>4, kg=t&15):
// 1 q-row x 4 k, reg double-buffered score h-loop and PV k4-loop.
// No online max (|score| <= sum|wv| uniform bound).
// FIX vs r13: V rows walk plain k4 order; p column ((k4+tq)&15) retrieves
// group k4 -> p and V consistently paired (r13 rotated V rows too: wrong).
// ---------------------------------------------------------------------------
__global__ __launch_bounds__(256, 4) void fused_kernel(
    const float* __restrict__ eqp, const float* __restrict__ ekp,
    const float* __restrict__ vglob, const float* __restrict__ wv,
    const int* __restrict__ vlens, float* __restrict__ part_o,
    float* __restrict__ part_l) {
  // ---- uniform worklist mapping (scalar) ----
  int pre[9];
  pre[0] = 0;
#pragma unroll
  for (int bb = 0; bb < 8; ++bb) {
    int nt = (vlens[bb] + 63) >> 6;
    nt = nt < 16 ? nt : 16;
    const int nch = (nt + KTPC - 1) / KTPC;
    pre[bb + 1] = pre[bb] + (nch << 6);  // nch chunks x 64 q-tiles
  }
  const int g = blockIdx.x;
  if (g >= pre[8]) return;
  int b = 0;
#pragma unroll
  for (int i = 0; i < 7; ++i) b += (g >= pre[i + 1]);
  const int local = g - pre[b];
  const int qt = local & 63;   // q-tile fastest (adjacent blocks share chunk)
  const int ch = local >> 6;
  const int q0 = qt * 16;
  const int vlen = vlens[b];
  int nt = (vlen + 63) >> 6;
  nt = nt < 16 ? nt : 16;
  const int kt0 = ch * KTPC;
  const int ktend = (kt0 + KTPC < nt) ? kt0 + KTPC : nt;

  __shared__ __align__(16) float qs[16][68];  // +4 pad: 4 wave-rows distinct banks
  __shared__ __align__(16) float ps[16][64];  // column-rotated by row
  const int t = threadIdx.x;
  const int tq = t >> 4;           // q row 0..15
  const int kg = t & 15;           // k group / d group
  const int kbs = kg << 2;
  const int pcol = (kg + tq) & 15; // rotated ps column (holds group kg)

  float sumw = 0.0f, sumabs = 0.0f;
#pragma unroll
  for (int h = 0; h < 64; ++h) {   // uniform -> scalar loads
    const float w = wv[h];
    sumw += w;
    sumabs += fabsf(w);
  }
  const float sbias = sumw - sumabs;  // s' = -2*acc + sbias <= 0 always

  {  // Q rows: 16x64 floats = 256 float4, one per thread; single barrier.
    const int r = t >> 4, sl = t & 15;
    *(float4*)&qs[r][sl * 4] =
        *(const float4*)&eqp[(long long)(b * QDIM + q0 + r) * 64 + sl * 4];
  }
  __syncthreads();

  float4 o4 = make_float4(0.0f, 0.0f, 0.0f, 0.0f);
  float l = 0.0f;

  for (int kt = kt0; kt < ktend; ++kt) {
    // K fragment base: rows kbs..kbs+3 are contiguous (256B apart)
    const float* pK = ekp + ((long long)(b * KDIM + kt * 64 + kbs)) * 64;
    const float* pV = vglob + ((long long)(b * KDIM + kt * 64)) * 64 + kbs;

    // ---- scores: reg double-buffered h-pipeline, K direct from L2 ----
    float acc0 = 0.0f, acc1 = 0.0f, acc2 = 0.0f, acc3 = 0.0f;
    float4 kA0, kA1, kA2, kA3;
    float4 kB0, kB1, kB2, kB3;

#define LOADG_K(K0, K1, K2, K3, H)               \
  K0 = *(const float4*)(pK + 0 * 64 + (H) * 4);  \
  K1 = *(const float4*)(pK + 1 * 64 + (H) * 4);  \
  K2 = *(const float4*)(pK + 2 * 64 + (H) * 4);  \
  K3 = *(const float4*)(pK + 3 * 64 + (H) * 4);

// quad rational: acc += (n01*d23 + n23*d01) * rcp(d01*d23), ui = 1+Eq*Ek
#define QUAD(ACC, QF, KF, W0, W1, W2, W3)                  \
  {                                                        \
    const float u0 = fmaf(QF.x, KF.x, 1.0f);               \
    const float u1 = fmaf(QF.y, KF.y, 1.0f);               \
    const float u2 = fmaf(QF.z, KF.z, 1.0f);               \
    const float u3 = fmaf(QF.w, KF.w, 1.0f);               \
    const float d01 = u0 * u1;                             \
    const float d23 = u2 * u3;                             \
    const float n01 = fmaf(W1, u0, W0 * u1);               \
    const float n23 = fmaf(W3, u2, W2 * u3);               \
    const float num = fmaf(n23, d01, n01 * d23);           \
    ACC = fmaf(num, __builtin_amdgcn_rcpf(d01 * d23), ACC);\
  }

#define COMP_STAGE(K0, K1, K2, K3, H)                      \
  {                                                        \
    const float4 q4 = *(const float4*)&qs[tq][(H) * 4];    \
    const float w0 = wv[(H) * 4 + 0];                      \
    const float w1 = wv[(H) * 4 + 1];                      \
    const float w2 = wv[(H) * 4 + 2];                      \
    const float w3 = wv[(H) * 4 + 3];                      \
    QUAD(acc0, q4, K0, w0, w1, w2, w3)                     \
    QUAD(acc1, q4, K1, w0, w1, w2, w3)                     \
    QUAD(acc2, q4, K2, w0, w1, w2, w3)                     \
    QUAD(acc3, q4, K3, w0, w1, w2, w3)                     \
  }

    LOADG_K(kA0, kA1, kA2, kA3, 0)
    LOADG_K(kB0, kB1, kB2, kB3, 1)
#pragma unroll
    for (int h = 0; h < 16; h += 2) {
      COMP_STAGE(kA0, kA1, kA2, kA3, h)
      if (h + 2 < 16) LOADG_K(kA0, kA1, kA2, kA3, h + 2)
      COMP_STAGE(kB0, kB1, kB2, kB3, h + 1)
      if (h + 3 < 16) LOADG_K(kB0, kB1, kB2, kB3, h + 3)
    }
#undef LOADG_K
#undef COMP_STAGE
#undef QUAD

    // ---- p = exp2(s - sumabs); masked lanes -> exact 0; no reductions ----
    const int kgl = kt * 64 + kbs;
    float s0 = (kgl + 0 < vlen) ? fmaf(-2.0f, acc0, sbias) : -3.0e38f;
    float s1 = (kgl + 1 < vlen) ? fmaf(-2.0f, acc1, sbias) : -3.0e38f;
    float s2 = (kgl + 2 < vlen) ? fmaf(-2.0f, acc2, sbias) : -3.0e38f;
    float s3 = (kgl + 3 < vlen) ? fmaf(-2.0f, acc3, sbias) : -3.0e38f;
    const float p0 = __builtin_amdgcn_exp2f(s0 * kLog2e);
    const float p1 = __builtin_amdgcn_exp2f(s1 * kLog2e);
    const float p2 = __builtin_amdgcn_exp2f(s2 * kLog2e);
    const float p3 = __builtin_amdgcn_exp2f(s3 * kLog2e);
    l += (p0 + p1) + (p2 + p3);
    // rotated store; produce/consume is wave-internal (row = 16 lanes in-wave)
    *(float4*)&ps[tq][pcol * 4] = make_float4(p0, p1, p2, p3);

    // ---- PV: o4 += sum_k p[k] * V[k][kbs..kbs+3], V direct from L2,
    //      reg double-buffered over k4. p col ((k4+tq)&15) == group k4. ----
    float4 vA0, vA1, vA2, vA3;
    float4 vB0, vB1, vB2, vB3;

#define LOADG_V(V0, V1, V2, V3, K4)                    \
  V0 = *(const float4*)(pV + ((K4) * 4 + 0) * 64);     \
  V1 = *(const float4*)(pV + ((K4) * 4 + 1) * 64);     \
  V2 = *(const float4*)(pV + ((K4) * 4 + 2) * 64);     \
  V3 = *(const float4*)(pV + ((K4) * 4 + 3) * 64);

#define PV_STAGE(V0, V1, V2, V3, K4)                           \
  {                                                            \
    const float4 p4 = *(const float4*)&ps[tq][(((K4) + tq) & 15) * 4]; \
    o4.x = fmaf(p4.x, V0.x, o4.x);                             \
    o4.y = fmaf(p4.x, V0.y, o4.y);                             \
    o4.z = fmaf(p4.x, V0.z, o4.z);                             \
    o4.w = fmaf(p4.x, V0.w, o4.w);                             \
    o4.x = fmaf(p4.y, V1.x, o4.x);                             \
    o4.y = fmaf(p4.y, V1.y, o4.y);                             \
    o4.z = fmaf(p4.y, V1.z, o4.z);                             \
    o4.w = fmaf(p4.y, V1.w, o4.w);                             \
    o4.x = fmaf(p4.z, V2.x, o4.x);                             \
    o4.y = fmaf(p4.z, V2.y, o4.y);                             \
    o4.z = fmaf(p4.z, V2.z, o4.z);                             \
    o4.w = fmaf(p4.z, V2.w, o4.w);                             \
    o4.x = fmaf(p4.w, V3.x, o4.x);                             \
    o4.y = fmaf(p4.w, V3.y, o4.y);                             \
    o4.z = fmaf(p4.w, V3.z, o4.z);                             \
    o4.w = fmaf(p4.w, V3.w, o4.w);                             \
  }

    LOADG_V(vA0, vA1, vA2, vA3, 0)
    LOADG_V(vB0, vB1, vB2, vB3, 1)
#pragma unroll
    for (int k4 = 0; k4 < 16; k4 += 2) {
      PV_STAGE(vA0, vA1, vA2, vA3, k4 + 0)
      if (k4 + 2 < 16) LOADG_V(vA0, vA1, vA2, vA3, k4 + 2)
      PV_STAGE(vB0, vB1, vB2, vB3, k4 + 1)
      if (k4 + 3 < 16) LOADG_V(vB0, vB1, vB2, vB3, k4 + 3)
    }
#undef LOADG_V
#undef PV_STAGE
  }

  // ---- reduce l over the 16 kg lanes (in-wave), write chunk partials ----
#pragma unroll
  for (int s = 1; s < 16; s <<= 1) l += __shfl_xor(l, s, 64);
  *(float4*)&part_o[((long long)g * 16 + tq) * 64 + kbs] = o4;
  if (kg == 0) part_l[g * 16 + tq] = l;
}

// ---------------------------------------------------------------------------
// K3: combine <=MAXCH chunk partials per q-row: plain sums (common shift
// cancels). 256 thr = 4 rows x 64 lanes.
// ---------------------------------------------------------------------------
__global__ __launch_bounds__(256) void combine_kernel(
    const float* __restrict__ part_o, const float* __restrict__ part_l,
    const int* __restrict__ vlens, float* __restrict__ out) {
  int pre[8], nchv[8];
  int run = 0;
#pragma unroll
  for (int bb = 0; bb < 8; ++bb) {
    int nt = (vlens[bb] + 63) >> 6;
    nt = nt < 16 ? nt : 16;
    nchv[bb] = (nt + KTPC - 1) / KTPC;
    pre[bb] = run;
    run += nchv[bb] << 6;
  }
  const int t = threadIdx.x;
  const int row = blockIdx.x * 4 + (t >> 6);
  const int lane = t & 63;
  const int b = row >> 10;
  const int q = row & (QDIM - 1);
  const int qt = q >> 4;
  const int tq = q & 15;
  const int nch = nchv[b];
  const int slot0 = pre[b] + qt;  // slot for chunk c = slot0 + c*64

  float L = 0.0f, acc = 0.0f;
#pragma unroll
  for (int c = 0; c < MAXCH; ++c) {
    if (c < nch) {
      L += part_l[(slot0 + (c << 6)) * 16 + tq];
      acc += part_o[((long long)(slot0 + (c << 6)) * 16 + tq) * 64 + lane];
    }
  }
  out[(long long)row * 64 + lane] = acc * __builtin_amdgcn_rcpf(L);
}

// ---------------------------------------------------------------------------
extern "C" void kernel_launch(void* const* d_in, const int* in_sizes, int n_in,
                              void* d_out, int out_size, void* d_ws, size_t ws_size,
                              hipStream_t stream) {
  const float* queries = (const float*)d_in[0];
  const float* keys    = (const float*)d_in[1];
  const float* values  = (const float*)d_in[2];
  const int*   vlens   = (const int*)d_in[3];
  const float* Wq      = (const float*)d_in[4];
  const float* Wk      = (const float*)d_in[5];
  const float* wv      = (const float*)d_in[6];
  float* out = (float*)d_out;

  float* eq     = (float*)d_ws;                      // B*Q*H = 2 MB
  float* ek     = eq + (size_t)BDIM * QDIM * HDIM;   // B*K*H = 2 MB
  float* part_o = ek + (size_t)BDIM * KDIM * HDIM;   // 4096*16*64*4 = 16.8 MB
  float* part_l = part_o + (size_t)4096 * 16 * 64;   // 256 KB

  proj_both<<<dim3(512), 256, 0, stream>>>(queries, keys, Wq, Wk, eq, ek);
  // max worklist = 8 b * 8 chunks * 64 q-tiles = 4096; invalid tail exits.
  fused_kernel<<<dim3(4096), 256, 0, stream>>>(eq, ek, values, wv, vlens,
                                               part_o, part_l);
  combine_kernel<<<dim3(BDIM * QDIM / 4), 256, 0, stream>>>(part_o, part_l,
                                                            vlens, out);
}

// Round 15
// 108.262 us; speedup vs baseline: 1.6825x; 1.6825x over previous
//
#include <hip/hip_runtime.h>

// Problem sizes (fixed by the reference)
#define BDIM 8
#define QDIM 1024
#define KDIM 1024
#define HDIM 64   // = DQ = DK = DV
#define KTPC 2    // k-tiles (64 keys) per chunk -> uniform block cost
#define MAXCH 8   // ceil(16/KTPC)

constexpr float kLog2e = 1.4426950408889634f;
constexpr float kC2 = 2.0f * kLog2e;

// ---------------------------------------------------------------------------
// K1: both projections; emits Eq/Ek = min(exp2(kC2 * (X@W)), 2^15).
// ---------------------------------------------------------------------------
__global__ __launch_bounds__(256) void proj_both(
    const float* __restrict__ queries, const float* __restrict__ keys,
    const float* __restrict__ Wq, const float* __restrict__ Wk,
    float* __restrict__ eq, float* __restrict__ ek) {
  const int bid = blockIdx.x;
  const bool isK = bid >= 256;
  const float* X = isK ? keys : queries;
  const float* W = isK ? Wk : Wq;
  float* Y = isK ? ek : eq;
  const long long base = (long long)(bid & 255) * 32 * 64;

  __shared__ __align__(16) float xs[32][68];
  __shared__ __align__(16) float ws[64][64];
  const int t = threadIdx.x;
  {
    const int r = t >> 4, sl = t & 15;
#pragma unroll
    for (int i = 0; i < 2; ++i)
      *(float4*)&xs[r + i * 16][sl * 4] =
          *(const float4*)&X[base + (long long)(r + i * 16) * 64 + sl * 4];
#pragma unroll
    for (int i = 0; i < 4; ++i)
      *(float4*)&ws[r + i * 16][sl * 4] =
          *(const float4*)&W[(r + i * 16) * 64 + sl * 4];
  }
  __syncthreads();

  const int r = t >> 3;            // 0..31
  const int c0 = (t & 7) * 8;      // 8 output cols per thread
  float acc[8];
#pragma unroll
  for (int j = 0; j < 8; ++j) acc[j] = 0.0f;

#pragma unroll 8
  for (int d = 0; d < 64; ++d) {
    const float xv = xs[r][d];
#pragma unroll
    for (int j4 = 0; j4 < 2; ++j4) {
      float4 w4 = *(float4*)&ws[d][c0 + j4 * 4];
      acc[j4 * 4 + 0] = fmaf(xv, w4.x, acc[j4 * 4 + 0]);
      acc[j4 * 4 + 1] = fmaf(xv, w4.y, acc[j4 * 4 + 1]);
      acc[j4 * 4 + 2] = fmaf(xv, w4.z, acc[j4 * 4 + 2]);
      acc[j4 * 4 + 3] = fmaf(xv, w4.w, acc[j4 * 4 + 3]);
    }
  }
#pragma unroll
  for (int j4 = 0; j4 < 2; ++j4) {
    float4 o = make_float4(
        fminf(__builtin_amdgcn_exp2f(acc[j4 * 4 + 0] * kC2), 32768.0f),
        fminf(__builtin_amdgcn_exp2f(acc[j4 * 4 + 1] * kC2), 32768.0f),
        fminf(__builtin_amdgcn_exp2f(acc[j4 * 4 + 2] * kC2), 32768.0f),
        fminf(__builtin_amdgcn_exp2f(acc[j4 * 4 + 3] * kC2), 32768.0f));
    *(float4*)&Y[base + (long long)r * 64 + c0 + j4 * 4] = o;
  }
}

// ---------------------------------------------------------------------------
// K2: fused scores + softmax-numerator + PV over one chunk (<=2 k-tiles).
// R11 structure (measured best: 4 blocks/CU, 73% VALUBusy) with two DS cuts:
//  (1) Q row held in REGISTERS (16 float4, compile-time indexed) -> removes
//      all qs LDS reads (-10% DS instr; DS was co-saturated with VALU).
//  (2) ps padded [16][68], natural columns (conflict-free by pad).
// LDS = ks 16K + vs 16K + ps 4.25K = 37.1 KB -> 4 blocks/CU retained.
// K/V staged in LDS (wave-dup reads broadcast for free there — round 14
// proved direct-global replication thrashes L2). No online max.
// ---------------------------------------------------------------------------
__global__ __launch_bounds__(256, 4) void fused_kernel(
    const float* __restrict__ eqp, const float* __restrict__ ekp,
    const float* __restrict__ vglob, const float* __restrict__ wv,
    const int* __restrict__ vlens, float* __restrict__ part_o,
    float* __restrict__ part_l) {
  // ---- uniform worklist mapping (scalar) ----
  int pre[9];
  pre[0] = 0;
#pragma unroll
  for (int bb = 0; bb < 8; ++bb) {
    int nt = (vlens[bb] + 63) >> 6;
    nt = nt < 16 ? nt : 16;
    const int nch = (nt + KTPC - 1) / KTPC;
    pre[bb + 1] = pre[bb] + (nch << 6);  // nch chunks x 64 q-tiles
  }
  const int g = blockIdx.x;
  if (g >= pre[8]) return;
  int b = 0;
#pragma unroll
  for (int i = 0; i < 7; ++i) b += (g >= pre[i + 1]);
  const int local = g - pre[b];
  const int qt = local & 63;   // q-tile fastest (adjacent blocks share chunk)
  const int ch = local >> 6;
  const int q0 = qt * 16;
  const int vlen = vlens[b];
  int nt = (vlen + 63) >> 6;
  nt = nt < 16 ? nt : 16;
  const int kt0 = ch * KTPC;
  const int ktend = (kt0 + KTPC < nt) ? kt0 + KTPC : nt;

  __shared__ __align__(16) float ks[64][64];  // 16 KB XOR-swizzled Ek
  __shared__ __align__(16) float vs[64][64];  // 16 KB V (linear)
  __shared__ __align__(16) float ps[16][68];  // 4.25 KB (+4 pad -> no conflicts)
  const int t = threadIdx.x;
  const int tq = t >> 4;           // q row 0..15
  const int kg = t & 15;           // k group / d group
  const int kbs = kg << 2;
  const int key0 = ((kbs + 0) ^ kg) & 15;
  const int key1 = ((kbs + 1) ^ kg) & 15;
  const int key2 = ((kbs + 2) ^ kg) & 15;
  const int key3 = ((kbs + 3) ^ kg) & 15;

  float sumw = 0.0f, sumabs = 0.0f;
#pragma unroll
  for (int h = 0; h < 64; ++h) {   // uniform -> scalar loads
    const float w = wv[h];
    sumw += w;
    sumabs += fabsf(w);
  }
  const float sbias = sumw - sumabs;  // s' = -2*acc + sbias <= 0 always

  // ---- Q row -> registers (16 kg lanes read the same row: coalesced) ----
  float4 qreg[16];
  {
    const float4* qrow =
        (const float4*)&eqp[(long long)(b * QDIM + q0 + tq) * 64];
#pragma unroll
    for (int i = 0; i < 16; ++i) qreg[i] = qrow[i];
  }

  float4 o4 = make_float4(0.0f, 0.0f, 0.0f, 0.0f);
  float l = 0.0f;

  for (int kt = kt0; kt < ktend; ++kt) {
    __syncthreads();  // prev iteration done reading ks/vs
    // stage Ek (swizzled) + V (linear): 4 float4 each per thread
#pragma unroll
    for (int i = 0; i < 4; ++i) {
      const int f = i * 256 + t;
      const int k = f >> 4, sl = f & 15;
      const int key = (k ^ (k >> 2)) & 15;
      const long long grow = (long long)(b * KDIM + kt * 64 + k) * 64 + sl * 4;
      *(float4*)&ks[k][(sl ^ key) * 4] = *(const float4*)&ekp[grow];
      *(float4*)&vs[k][sl * 4] = *(const float4*)&vglob[grow];
    }
    __syncthreads();

    // ---- scores for (tq, kbs..kbs+3): reg double-buffered h-pipeline ----
    float acc0 = 0.0f, acc1 = 0.0f, acc2 = 0.0f, acc3 = 0.0f;
    float4 kA0, kA1, kA2, kA3;
    float4 kB0, kB1, kB2, kB3;

#define LOAD_STAGE(K0, K1, K2, K3, H)                      \
  K0 = *(const float4*)&ks[kbs + 0][((H) ^ key0) * 4];     \
  K1 = *(const float4*)&ks[kbs + 1][((H) ^ key1) * 4];     \
  K2 = *(const float4*)&ks[kbs + 2][((H) ^ key2) * 4];     \
  K3 = *(const float4*)&ks[kbs + 3][((H) ^ key3) * 4];

// quad rational: acc += (n01*d23 + n23*d01) * rcp(d01*d23), ui = 1+Eq*Ek
#define QUAD(ACC, QF, KF, W0, W1, W2, W3)                  \
  {                                                        \
    const float u0 = fmaf(QF.x, KF.x, 1.0f);               \
    const float u1 = fmaf(QF.y, KF.y, 1.0f);               \
    const float u2 = fmaf(QF.z, KF.z, 1.0f);               \
    const float u3 = fmaf(QF.w, KF.w, 1.0f);               \
    const float d01 = u0 * u1;                             \
    const float d23 = u2 * u3;                             \
    const float n01 = fmaf(W1, u0, W0 * u1);               \
    const float n23 = fmaf(W3, u2, W2 * u3);               \
    const float num = fmaf(n23, d01, n01 * d23);           \
    ACC = fmaf(num, __builtin_amdgcn_rcpf(d01 * d23), ACC);\
  }

#define COMP_STAGE(K0, K1, K2, K3, H)                      \
  {                                                        \
    const float4 q4 = qreg[(H)];                           \
    const float w0 = wv[(H) * 4 + 0];                      \
    const float w1 = wv[(H) * 4 + 1];                      \
    const float w2 = wv[(H) * 4 + 2];                      \
    const float w3 = wv[(H) * 4 + 3];                      \
    QUAD(acc0, q4, K0, w0, w1, w2, w3)                     \
    QUAD(acc1, q4, K1, w0, w1, w2, w3)                     \
    QUAD(acc2, q4, K2, w0, w1, w2, w3)                     \
    QUAD(acc3, q4, K3, w0, w1, w2, w3)                     \
  }

    LOAD_STAGE(kA0, kA1, kA2, kA3, 0)
#pragma unroll
    for (int h = 0; h < 16; h += 2) {
      LOAD_STAGE(kB0, kB1, kB2, kB3, h + 1)
      COMP_STAGE(kA0, kA1, kA2, kA3, h)
      if (h + 2 < 16) LOAD_STAGE(kA0, kA1, kA2, kA3, h + 2)
      COMP_STAGE(kB0, kB1, kB2, kB3, h + 1)
    }
#undef LOAD_STAGE
#undef COMP_STAGE
#undef QUAD

    // ---- p = exp2(s - sumabs); masked lanes -> exact 0; no reductions ----
    const int kgl = kt * 64 + kbs;
    float s0 = (kgl + 0 < vlen) ? fmaf(-2.0f, acc0, sbias) : -3.0e38f;
    float s1 = (kgl + 1 < vlen) ? fmaf(-2.0f, acc1, sbias) : -3.0e38f;
    float s2 = (kgl + 2 < vlen) ? fmaf(-2.0f, acc2, sbias) : -3.0e38f;
    float s3 = (kgl + 3 < vlen) ? fmaf(-2.0f, acc3, sbias) : -3.0e38f;
    const float p0 = __builtin_amdgcn_exp2f(s0 * kLog2e);
    const float p1 = __builtin_amdgcn_exp2f(s1 * kLog2e);
    const float p2 = __builtin_amdgcn_exp2f(s2 * kLog2e);
    const float p3 = __builtin_amdgcn_exp2f(s3 * kLog2e);
    l += (p0 + p1) + (p2 + p3);
    // produce/consume is wave-internal (row's 16 lanes in one wave): no barrier
    *(float4*)&ps[tq][kbs] = make_float4(p0, p1, p2, p3);

    // ---- PV: o4 += sum_k ps[tq][k] * vs[k][kbs..kbs+3] ----
#pragma unroll 4
    for (int k4 = 0; k4 < 16; ++k4) {
      const float4 p4 = *(const float4*)&ps[tq][k4 * 4];
      const float pw[4] = {p4.x, p4.y, p4.z, p4.w};
#pragma unroll
      for (int e = 0; e < 4; ++e) {
        const float4 vv = *(const float4*)&vs[k4 * 4 + e][kbs];
        o4.x = fmaf(pw[e], vv.x, o4.x);
        o4.y = fmaf(pw[e], vv.y, o4.y);
        o4.z = fmaf(pw[e], vv.z, o4.z);
        o4.w = fmaf(pw[e], vv.w, o4.w);
      }
    }
  }

  // ---- reduce l over the 16 kg lanes (in-wave), write chunk partials ----
#pragma unroll
  for (int s = 1; s < 16; s <<= 1) l += __shfl_xor(l, s, 64);
  *(float4*)&part_o[((long long)g * 16 + tq) * 64 + kbs] = o4;
  if (kg == 0) part_l[g * 16 + tq] = l;
}

// ---------------------------------------------------------------------------
// K3: combine <=MAXCH chunk partials per q-row: plain sums (common shift
// cancels). 256 thr = 4 rows x 64 lanes.
// ---------------------------------------------------------------------------
__global__ __launch_bounds__(256) void combine_kernel(
    const float* __restrict__ part_o, const float* __restrict__ part_l,
    const int* __restrict__ vlens, float* __restrict__ out) {
  int pre[8], nchv[8];
  int run = 0;
#pragma unroll
  for (int bb = 0; bb < 8; ++bb) {
    int nt = (vlens[bb] + 63) >> 6;
    nt = nt < 16 ? nt : 16;
    nchv[bb] = (nt + KTPC - 1) / KTPC;
    pre[bb] = run;
    run += nchv[bb] << 6;
  }
  const int t = threadIdx.x;
  const int row = blockIdx.x * 4 + (t >> 6);
  const int lane = t & 63;
  const int b = row >> 10;
  const int q = row & (QDIM - 1);
  const int qt = q >> 4;
  const int tq = q & 15;
  const int nch = nchv[b];
  const int slot0 = pre[b] + qt;  // slot for chunk c = slot0 + c*64

  float L = 0.0f, acc = 0.0f;
#pragma unroll
  for (int c = 0; c < MAXCH; ++c) {
    if (c < nch) {
      L += part_l[(slot0 + (c << 6)) * 16 + tq];
      acc += part_o[((long long)(slot0 + (c << 6)) * 16 + tq) * 64 + lane];
    }
  }
  out[(long long)row * 64 + lane] = acc * __builtin_amdgcn_rcpf(L);
}

// ---------------------------------------------------------------------------
extern "C" void kernel_launch(void* const* d_in, const int* in_sizes, int n_in,
                              void* d_out, int out_size, void* d_ws, size_t ws_size,
                              hipStream_t stream) {
  const float* queries = (const float*)d_in[0];
  const float* keys    = (const float*)d_in[1];
  const float* values  = (const float*)d_in[2];
  const int*   vlens   = (const int*)d_in[3];
  const float* Wq      = (const float*)d_in[4];
  const float* Wk      = (const float*)d_in[5];
  const float* wv      = (const float*)d_in[6];
  float* out = (float*)d_out;

  float* eq     = (float*)d_ws;                      // B*Q*H = 2 MB
  float* ek     = eq + (size_t)BDIM * QDIM * HDIM;   // B*K*H = 2 MB
  float* part_o = ek + (size_t)BDIM * KDIM * HDIM;   // 4096*16*64*4 = 16.8 MB
  float* part_l = part_o + (size_t)4096 * 16 * 64;   // 256 KB

  proj_both<<<dim3(512), 256, 0, stream>>>(queries, keys, Wq, Wk, eq, ek);
  // max worklist = 8 b * 8 chunks * 64 q-tiles = 4096; invalid tail exits.
  fused_kernel<<<dim3(4096), 256, 0, stream>>>(eq, ek, values, wv, vlens,
                                               part_o, part_l);
  combine_kernel<<<dim3(BDIM * QDIM / 4), 256, 0, stream>>>(part_o, part_l,
                                                            vlens, out);
}

// Round 16
// 52.562 us; speedup vs baseline: 3.4654x; 2.0597x over previous
//
#include <hip/hip_runtime.h>

// Problem sizes (fixed by the reference)
#define BDIM 8
#define QDIM 1024
#define KDIM 1024
#define HDIM 64   // = DQ = DK = DV
#define KTPC 2    // k-tiles (64 keys) per chunk -> uniform block cost
#define MAXCH 8   // ceil(16/KTPC)

constexpr float kLog2e = 1.4426950408889634f;
constexpr float kC2 = 2.0f * kLog2e;

// direct global->LDS copy, 16B per lane (no VGPR round-trip).
// LDS dest must be linear in lane order (wave-uniform base + lane*16).
__device__ __forceinline__ void load_lds16(const float* g, float* l) {
  __builtin_amdgcn_global_load_lds(
      (const __attribute__((address_space(1))) void*)g,
      (__attribute__((address_space(3))) void*)l, 16, 0, 0);
}

// ---------------------------------------------------------------------------
// K1: both projections; emits Eq/Ek = min(exp2(kC2 * (X@W)), 2^15).
// ---------------------------------------------------------------------------
__global__ __launch_bounds__(256) void proj_both(
    const float* __restrict__ queries, const float* __restrict__ keys,
    const float* __restrict__ Wq, const float* __restrict__ Wk,
    float* __restrict__ eq, float* __restrict__ ek) {
  const int bid = blockIdx.x;
  const bool isK = bid >= 256;
  const float* X = isK ? keys : queries;
  const float* W = isK ? Wk : Wq;
  float* Y = isK ? ek : eq;
  const long long base = (long long)(bid & 255) * 32 * 64;

  __shared__ __align__(16) float xs[32][68];
  __shared__ __align__(16) float ws[64][64];
  const int t = threadIdx.x;
  {
    const int r = t >> 4, sl = t & 15;
#pragma unroll
    for (int i = 0; i < 2; ++i)
      *(float4*)&xs[r + i * 16][sl * 4] =
          *(const float4*)&X[base + (long long)(r + i * 16) * 64 + sl * 4];
#pragma unroll
    for (int i = 0; i < 4; ++i)
      *(float4*)&ws[r + i * 16][sl * 4] =
          *(const float4*)&W[(r + i * 16) * 64 + sl * 4];
  }
  __syncthreads();

  const int r = t >> 3;            // 0..31
  const int c0 = (t & 7) * 8;      // 8 output cols per thread
  float acc[8];
#pragma unroll
  for (int j = 0; j < 8; ++j) acc[j] = 0.0f;

#pragma unroll 8
  for (int d = 0; d < 64; ++d) {
    const float xv = xs[r][d];
#pragma unroll
    for (int j4 = 0; j4 < 2; ++j4) {
      float4 w4 = *(float4*)&ws[d][c0 + j4 * 4];
      acc[j4 * 4 + 0] = fmaf(xv, w4.x, acc[j4 * 4 + 0]);
      acc[j4 * 4 + 1] = fmaf(xv, w4.y, acc[j4 * 4 + 1]);
      acc[j4 * 4 + 2] = fmaf(xv, w4.z, acc[j4 * 4 + 2]);
      acc[j4 * 4 + 3] = fmaf(xv, w4.w, acc[j4 * 4 + 3]);
    }
  }
#pragma unroll
  for (int j4 = 0; j4 < 2; ++j4) {
    float4 o = make_float4(
        fminf(__builtin_amdgcn_exp2f(acc[j4 * 4 + 0] * kC2), 32768.0f),
        fminf(__builtin_amdgcn_exp2f(acc[j4 * 4 + 1] * kC2), 32768.0f),
        fminf(__builtin_amdgcn_exp2f(acc[j4 * 4 + 2] * kC2), 32768.0f),
        fminf(__builtin_amdgcn_exp2f(acc[j4 * 4 + 3] * kC2), 32768.0f));
    *(float4*)&Y[base + (long long)r * 64 + c0 + j4 * 4] = o;
  }
}

// ---------------------------------------------------------------------------
// K2: fused scores + softmax-numerator + PV over one chunk (<=2 k-tiles).
// EXACT R11 structure (measured best: 44.7us, 73% VALUBusy, 4 blocks/CU,
// LDS 40KB, VGPR 64) with ONE change: ks/vs staging uses
// global_load_lds width=16 — direct to LDS, no VGPR round-trip.
// ks swizzle preserved by PRE-SWIZZLING THE GLOBAL SOURCE address
// (LDS dest must stay linear in lane order); vs linear both sides.
// __syncthreads() drains vmcnt(0) before reads. No online max
// (|score| <= sum|wv| uniform bound); ps rotated, wave-internal.
// ---------------------------------------------------------------------------
__global__ __launch_bounds__(256, 4) void fused_kernel(
    const float* __restrict__ eqp, const float* __restrict__ ekp,
    const float* __restrict__ vglob, const float* __restrict__ wv,
    const int* __restrict__ vlens, float* __restrict__ part_o,
    float* __restrict__ part_l) {
  // ---- uniform worklist mapping (scalar) ----
  int pre[9];
  pre[0] = 0;
#pragma unroll
  for (int bb = 0; bb < 8; ++bb) {
    int nt = (vlens[bb] + 63) >> 6;
    nt = nt < 16 ? nt : 16;
    const int nch = (nt + KTPC - 1) / KTPC;
    pre[bb + 1] = pre[bb] + (nch << 6);  // nch chunks x 64 q-tiles
  }
  const int g = blockIdx.x;
  if (g >= pre[8]) return;
  int b = 0;
#pragma unroll
  for (int i = 0; i < 7; ++i) b += (g >= pre[i + 1]);
  const int local = g - pre[b];
  const int qt = local & 63;   // q-tile fastest (adjacent blocks share chunk)
  const int ch = local >> 6;
  const int q0 = qt * 16;
  const int vlen = vlens[b];
  int nt = (vlen + 63) >> 6;
  nt = nt < 16 ? nt : 16;
  const int kt0 = ch * KTPC;
  const int ktend = (kt0 + KTPC < nt) ? kt0 + KTPC : nt;

  __shared__ __align__(16) float qs[16][64];  // broadcast reads
  __shared__ __align__(16) float ks[64][64];  // XOR-swizzled Ek (via global src)
  __shared__ __align__(16) float vs[64][64];  // V (linear)
  __shared__ __align__(16) float ps[16][64];  // column-rotated by row
  const int t = threadIdx.x;
  const int tq = t >> 4;           // q row 0..15
  const int kg = t & 15;           // k group / d group
  const int kbs = kg << 2;
  const int key0 = ((kbs + 0) ^ kg) & 15;
  const int key1 = ((kbs + 1) ^ kg) & 15;
  const int key2 = ((kbs + 2) ^ kg) & 15;
  const int key3 = ((kbs + 3) ^ kg) & 15;
  const int pcol = (kg + tq) & 15; // rotated ps column (holds group kg)

  float sumw = 0.0f, sumabs = 0.0f;
#pragma unroll
  for (int h = 0; h < 64; ++h) {   // uniform -> scalar loads
    const float w = wv[h];
    sumw += w;
    sumabs += fabsf(w);
  }
  const float sbias = sumw - sumabs;  // s' = -2*acc + sbias <= 0 always

  {  // Q rows: 16x64 floats = 256 float4, one per thread (lane-linear).
    const int r = t >> 4, sl = t & 15;
    load_lds16(&eqp[(long long)(b * QDIM + q0 + r) * 64 + sl * 4],
               &qs[0][0] + t * 4);
  }

  // per-lane staging indices (constant across tiles)
  const int sk[4] = {(t + 0) >> 4, (t + 256) >> 4, (t + 512) >> 4,
                     (t + 768) >> 4};
  const int ssl = t & 15;

  float4 o4 = make_float4(0.0f, 0.0f, 0.0f, 0.0f);
  float l = 0.0f;

  for (int kt = kt0; kt < ktend; ++kt) {
    __syncthreads();  // prev iteration done reading ks/vs (+ Q landed, iter 1)
    // stage Ek (global-src pre-swizzled) + V (linear): 4 x 16B each, direct
#pragma unroll
    for (int i = 0; i < 4; ++i) {
      const int f = i * 256 + t;
      const int k = sk[i];
      const int key = (k ^ (k >> 2)) & 15;
      const long long grow = (long long)(b * KDIM + kt * 64 + k) * 64;
      load_lds16(&ekp[grow + ((ssl ^ key) << 2)], &ks[0][0] + f * 4);
      load_lds16(&vglob[grow + (ssl << 2)], &vs[0][0] + f * 4);
    }
    __syncthreads();  // drains vmcnt(0): ks/vs visible

    // ---- scores for (tq, kbs..kbs+3): reg double-buffered h-pipeline ----
    float acc0 = 0.0f, acc1 = 0.0f, acc2 = 0.0f, acc3 = 0.0f;
    float4 qA, kA0, kA1, kA2, kA3;
    float4 qB, kB0, kB1, kB2, kB3;

#define LOAD_STAGE(QF, K0, K1, K2, K3, H)                  \
  QF = *(const float4*)&qs[tq][(H) * 4];                   \
  K0 = *(const float4*)&ks[kbs + 0][((H) ^ key0) * 4];     \
  K1 = *(const float4*)&ks[kbs + 1][((H) ^ key1) * 4];     \
  K2 = *(const float4*)&ks[kbs + 2][((H) ^ key2) * 4];     \
  K3 = *(const float4*)&ks[kbs + 3][((H) ^ key3) * 4];

// quad rational: acc += (n01*d23 + n23*d01) * rcp(d01*d23), ui = 1+Eq*Ek
#define QUAD(ACC, QF, KF, W0, W1, W2, W3)                  \
  {                                                        \
    const float u0 = fmaf(QF.x, KF.x, 1.0f);               \
    const float u1 = fmaf(QF.y, KF.y, 1.0f);               \
    const float u2 = fmaf(QF.z, KF.z, 1.0f);               \
    const float u3 = fmaf(QF.w, KF.w, 1.0f);               \
    const float d01 = u0 * u1;                             \
    const float d23 = u2 * u3;                             \
    const float n01 = fmaf(W1, u0, W0 * u1);               \
    const float n23 = fmaf(W3, u2, W2 * u3);               \
    const float num = fmaf(n23, d01, n01 * d23);           \
    ACC = fmaf(num, __builtin_amdgcn_rcpf(d01 * d23), ACC);\
  }

#define COMP_STAGE(QF, K0, K1, K2, K3, H)                  \
  {                                                        \
    const float w0 = wv[(H) * 4 + 0];                      \
    const float w1 = wv[(H) * 4 + 1];                      \
    const float w2 = wv[(H) * 4 + 2];                      \
    const float w3 = wv[(H) * 4 + 3];                      \
    QUAD(acc0, QF, K0, w0, w1, w2, w3)                     \
    QUAD(acc1, QF, K1, w0, w1, w2, w3)                     \
    QUAD(acc2, QF, K2, w0, w1, w2, w3)                     \
    QUAD(acc3, QF, K3, w0, w1, w2, w3)                     \
  }

    LOAD_STAGE(qA, kA0, kA1, kA2, kA3, 0)
#pragma unroll
    for (int h = 0; h < 16; h += 2) {
      LOAD_STAGE(qB, kB0, kB1, kB2, kB3, h + 1)
      COMP_STAGE(qA, kA0, kA1, kA2, kA3, h)
      if (h + 2 < 16) LOAD_STAGE(qA, kA0, kA1, kA2, kA3, h + 2)
      COMP_STAGE(qB, kB0, kB1, kB2, kB3, h + 1)
    }
#undef LOAD_STAGE
#undef COMP_STAGE
#undef QUAD

    // ---- p = exp2(s - sumabs); masked lanes -> exact 0; no reductions ----
    const int kgl = kt * 64 + kbs;
    float s0 = (kgl + 0 < vlen) ? fmaf(-2.0f, acc0, sbias) : -3.0e38f;
    float s1 = (kgl + 1 < vlen) ? fmaf(-2.0f, acc1, sbias) : -3.0e38f;
    float s2 = (kgl + 2 < vlen) ? fmaf(-2.0f, acc2, sbias) : -3.0e38f;
    float s3 = (kgl + 3 < vlen) ? fmaf(-2.0f, acc3, sbias) : -3.0e38f;
    const float p0 = __builtin_amdgcn_exp2f(s0 * kLog2e);
    const float p1 = __builtin_amdgcn_exp2f(s1 * kLog2e);
    const float p2 = __builtin_amdgcn_exp2f(s2 * kLog2e);
    const float p3 = __builtin_amdgcn_exp2f(s3 * kLog2e);
    l += (p0 + p1) + (p2 + p3);
    // rotated store; produce/consume is wave-internal (row = 16 lanes in-wave)
    *(float4*)&ps[tq][pcol * 4] = make_float4(p0, p1, p2, p3);

    // ---- PV: o4 += sum_k p[k] * vs[k][kbs..kbs+3] ----
    // p col ((k4+tq)&15) holds group k4 under the rotated-store scheme.
#pragma unroll 4
    for (int k4 = 0; k4 < 16; ++k4) {
      const float4 p4 = *(const float4*)&ps[tq][((k4 + tq) & 15) * 4];
      const float pw[4] = {p4.x, p4.y, p4.z, p4.w};
#pragma unroll
      for (int e = 0; e < 4; ++e) {
        const float4 vv = *(const float4*)&vs[k4 * 4 + e][kbs];
        o4.x = fmaf(pw[e], vv.x, o4.x);
        o4.y = fmaf(pw[e], vv.y, o4.y);
        o4.z = fmaf(pw[e], vv.z, o4.z);
        o4.w = fmaf(pw[e], vv.w, o4.w);
      }
    }
  }

  // ---- reduce l over the 16 kg lanes (in-wave), write chunk partials ----
#pragma unroll
  for (int s = 1; s < 16; s <<= 1) l += __shfl_xor(l, s, 64);
  *(float4*)&part_o[((long long)g * 16 + tq) * 64 + kbs] = o4;
  if (kg == 0) part_l[g * 16 + tq] = l;
}

// ---------------------------------------------------------------------------
// K3: combine <=MAXCH chunk partials per q-row: plain sums (common shift
// cancels). 256 thr = 4 rows x 64 lanes.
// ---------------------------------------------------------------------------
__global__ __launch_bounds__(256) void combine_kernel(
    const float* __restrict__ part_o, const float* __restrict__ part_l,
    const int* __restrict__ vlens, float* __restrict__ out) {
  int pre[8], nchv[8];
  int run = 0;
#pragma unroll
  for (int bb = 0; bb < 8; ++bb) {
    int nt = (vlens[bb] + 63) >> 6;
    nt = nt < 16 ? nt : 16;
    nchv[bb] = (nt + KTPC - 1) / KTPC;
    pre[bb] = run;
    run += nchv[bb] << 6;
  }
  const int t = threadIdx.x;
  const int row = blockIdx.x * 4 + (t >> 6);
  const int lane = t & 63;
  const int b = row >> 10;
  const int q = row & (QDIM - 1);
  const int qt = q >> 4;
  const int tq = q & 15;
  const int nch = nchv[b];
  const int slot0 = pre[b] + qt;  // slot for chunk c = slot0 + c*64

  float L = 0.0f, acc = 0.0f;
#pragma unroll
  for (int c = 0; c < MAXCH; ++c) {
    if (c < nch) {
      L += part_l[(slot0 + (c << 6)) * 16 + tq];
      acc += part_o[((long long)(slot0 + (c << 6)) * 16 + tq) * 64 + lane];
    }
  }
  out[(long long)row * 64 + lane] = acc * __builtin_amdgcn_rcpf(L);
}

// ---------------------------------------------------------------------------
extern "C" void kernel_launch(void* const* d_in, const int* in_sizes, int n_in,
                              void* d_out, int out_size, void* d_ws, size_t ws_size,
                              hipStream_t stream) {
  const float* queries = (const float*)d_in[0];
  const float* keys    = (const float*)d_in[1];
  const float* values  = (const float*)d_in[2];
  const int*   vlens   = (const int*)d_in[3];
  const float* Wq      = (const float*)d_in[4];
  const float* Wk      = (const float*)d_in[5];
  const float* wv      = (const float*)d_in[6];
  float* out = (float*)d_out;

  float* eq     = (float*)d_ws;                      // B*Q*H = 2 MB
  float* ek     = eq + (size_t)BDIM * QDIM * HDIM;   // B*K*H = 2 MB
  float* part_o = ek + (size_t)BDIM * KDIM * HDIM;   // 4096*16*64*4 = 16.8 MB
  float* part_l = part_o + (size_t)4096 * 16 * 64;   // 256 KB

  proj_both<<<dim3(512), 256, 0, stream>>>(queries, keys, Wq, Wk, eq, ek);
  // max worklist = 8 b * 8 chunks * 64 q-tiles = 4096; invalid tail exits.
  fused_kernel<<<dim3(4096), 256, 0, stream>>>(eq, ek, values, wv, vlens,
                                               part_o, part_l);
  combine_kernel<<<dim3(BDIM * QDIM / 4), 256, 0, stream>>>(part_o, part_l,
                                                            vlens, out);
}